// Round 4
// baseline (1986.471 us; speedup 1.0000x reference)
//
#include <hip/hip_runtime.h>
#include <stdint.h>

#define NE 8192
#define KD 512
#define MT 65536

typedef __attribute__((ext_vector_type(8))) short bf16x8;
typedef __attribute__((ext_vector_type(4))) float f32x4;

union U128 { uint4 u; bf16x8 b; };

// ---- workspace layout (bytes) ----
#define WS_SUMZ2   0                  // float
#define WS_SUMSMIN 4                  // float
#define WS_HIST    8                  // 8192 * int
#define WS_ZEROSZ  40960              // memset region covers the above
#define WS_E2      40960              // 8192 floats
#define WS_IDX     73728              // 65536 ints
#define WS_EMB16   335872             // 8192*512 bf16 (ushort)
#define WS_Z16     8724480            // 65536*512 bf16 (ushort)
// total ws needed: 75,833,344 bytes

__device__ __forceinline__ unsigned int f2bf(float f) {
    union { float f; unsigned int u; } c; c.f = f;
    return (c.u + 0x7FFFu + ((c.u >> 16) & 1u)) >> 16;
}

// ---------------- K0: emb -> bf16, e2 = ||e||^2 ----------------
__global__ void k_embprep(const float* __restrict__ emb,
                          unsigned short* __restrict__ emb16,
                          float* __restrict__ e2) {
    const int code = blockIdx.x;
    const int lane = threadIdx.x;  // 64
    const float4* row = (const float4*)(emb + (size_t)code * KD);
    float4 a = row[lane * 2];
    float4 b = row[lane * 2 + 1];
    float s = a.x*a.x + a.y*a.y + a.z*a.z + a.w*a.w
            + b.x*b.x + b.y*b.y + b.z*b.z + b.w*b.w;
    uint4 o;
    o.x = f2bf(a.x) | (f2bf(a.y) << 16);
    o.y = f2bf(a.z) | (f2bf(a.w) << 16);
    o.z = f2bf(b.x) | (f2bf(b.y) << 16);
    o.w = f2bf(b.z) | (f2bf(b.w) << 16);
    ((uint4*)(emb16 + (size_t)code * KD))[lane] = o;
    #pragma unroll
    for (int off = 32; off; off >>= 1) s += __shfl_down(s, off, 64);
    if (lane == 0) e2[code] = s;
}

// ---------------- K1: transpose z (N,C,T) -> z16[M][K] bf16, sum z^2 ----------------
__global__ void k_zprep(const float* __restrict__ z,
                        unsigned short* __restrict__ z16,
                        float* __restrict__ sumz2) {
    // grid: (32 t-tiles, 8 c-tiles, 32 n); 256 threads; tile = 64c x 64t
    __shared__ float arr[64][65];
    __shared__ float red[4];
    const int tid = threadIdx.x;
    const int n  = blockIdx.z;
    const int c0 = blockIdx.y * 64;
    const int t0 = blockIdx.x * 64;
    const int tl4 = (tid & 15) * 4;   // t offset (16B aligned)
    const int cw  = tid >> 4;         // 0..15
    const float* base = z + ((size_t)n * KD + c0) * 2048 + t0;
    float s = 0.f;
    #pragma unroll
    for (int u = 0; u < 4; u++) {
        int c = u * 16 + cw;
        float4 v = *(const float4*)(base + (size_t)c * 2048 + tl4);
        arr[c][tl4 + 0] = v.x; arr[c][tl4 + 1] = v.y;
        arr[c][tl4 + 2] = v.z; arr[c][tl4 + 3] = v.w;
        s += v.x*v.x + v.y*v.y + v.z*v.z + v.w*v.w;
    }
    #pragma unroll
    for (int off = 32; off; off >>= 1) s += __shfl_down(s, off, 64);
    if ((tid & 63) == 0) red[tid >> 6] = s;
    __syncthreads();
    if (tid == 0) atomicAdd(sumz2, red[0] + red[1] + red[2] + red[3]);
    #pragma unroll
    for (int iter = 0; iter < 2; iter++) {
        int task = iter * 256 + tid;
        int row = task >> 3;       // t index 0..63
        int ch  = task & 7;        // uint4 chunk (8 c's)
        float f0 = arr[ch*8+0][row], f1 = arr[ch*8+1][row],
              f2v = arr[ch*8+2][row], f3 = arr[ch*8+3][row],
              f4 = arr[ch*8+4][row], f5 = arr[ch*8+5][row],
              f6 = arr[ch*8+6][row], f7 = arr[ch*8+7][row];
        uint4 o;
        o.x = f2bf(f0) | (f2bf(f1) << 16);
        o.y = f2bf(f2v) | (f2bf(f3) << 16);
        o.z = f2bf(f4) | (f2bf(f5) << 16);
        o.w = f2bf(f6) | (f2bf(f7) << 16);
        *(uint4*)(z16 + ((size_t)(n * 2048 + t0 + row)) * KD + c0 + ch * 8) = o;
    }
}

// ---------------- K2: fused GEMM + argmin (barrier-free K-loop) ----------------
// A (z-tile) resident in LDS (128 KB, conflict-free XOR swizzle).
// B (emb16) loaded DIRECTLY global->registers per fragment: emb16 is L2/L3
// resident (all 512 blocks stream it in the same order), so the LDS round
// trip (stage 16KB + read 32KB per step) and ALL K-loop barriers are deleted.
// Distance-1 register ping-pong for both A-frags (afp) and B-frags (bfp):
// loads for step g+1 issue during step g's MFMAs; ~900 cyc of slack covers
// L2 latency. No __syncthreads between zt publication and the final reduce.
__global__ __launch_bounds__(512, 2) void k_main(
    const unsigned short* __restrict__ z16,   // [65536][512]
    const unsigned short* __restrict__ emb16, // [8192][512]
    const float* __restrict__ e2,             // [8192]
    int* __restrict__ g_idx,                  // [65536]
    int* __restrict__ hist,                   // [8192]
    float* __restrict__ sums)                 // ws base: [0]=sumz2, [1]=sumsmin
{
    __shared__ __align__(16) unsigned short zt[128 * 512];   // 131072 B, swizzled

    const int tid  = threadIdx.x;
    const int lane = tid & 63;
    const int w    = tid >> 6;       // 0..7
    const int wm   = w & 1;
    const int wn   = w >> 1;         // 0..3
    const int quad = lane >> 4;
    const int col  = lane & 15;
    const int m0   = blockIdx.x * 128;

    // ---- stage zt: rows m0..m0+127, full K, 16B-chunk XOR swizzle ----
    {
        const int r  = tid >> 2;             // 0..127
        const int jb = (tid & 3) << 4;       // 0,16,32,48
        const uint4* gz = (const uint4*)(z16 + (size_t)(m0 + r) * KD);
        uint4* zt4w = (uint4*)zt;
        #pragma unroll
        for (int jj = 0; jj < 16; jj++) {
            int j  = jb + jj;
            int js = (j & 56) | ((j ^ r) & 7);
            zt4w[r * 64 + js] = gz[j];
        }
    }

    f32x4 acc[4][4];
    #pragma unroll
    for (int mf = 0; mf < 4; mf++)
        #pragma unroll
        for (int nf = 0; nf < 4; nf++)
            acc[mf][nf] = (f32x4){0.f, 0.f, 0.f, 0.f};

    float rbv[4][4]; int rbi[4][4];
    #pragma unroll
    for (int mf = 0; mf < 4; mf++)
        #pragma unroll
        for (int rg = 0; rg < 4; rg++) { rbv[mf][rg] = 3.0e38f; rbi[mf][rg] = 0; }

    // A-read precompute
    int zbase[4], r7[4];
    #pragma unroll
    for (int mf = 0; mf < 4; mf++) {
        int r = wm * 64 + mf * 16 + col;
        zbase[mf] = r * 64;
        r7[mf] = r & 7;
    }
    // B global-read precompute: uint4 index of (code_local, quad) within a
    // (chunk,kk) slice base. code_local = wn*64 + nf*16 + col; row = 512 elem
    // = 64 uint4; quad selects the 16B sub-chunk of the 32-elem K-slice.
    int bgl[4];
    #pragma unroll
    for (int nf = 0; nf < 4; nf++)
        bgl[nf] = (wn * 64 + nf * 16 + col) * 64 + quad;

    const uint4* zt4 = (const uint4*)zt;

    __syncthreads();   // zt published; read-only from here to the final reduce

    // distance-1 register ping-pongs (self-limit compiler hoisting to 2 steps)
    bf16x8 afp[2][4], bfp[2][4];
    #pragma unroll
    for (int mf = 0; mf < 4; mf++) {
        U128 u; u.u = zt4[zbase[mf] + (quad ^ r7[mf])];
        afp[0][mf] = u.b;
    }
    {
        const uint4* bsrc = (const uint4*)emb16;   // chunk 0, kk 0
        #pragma unroll
        for (int nf = 0; nf < 4; nf++) {
            U128 u; u.u = bsrc[bgl[nf]];
            bfp[0][nf] = u.b;
        }
    }

    #pragma unroll 1
    for (int chunk = 0; chunk < 32; chunk++) {
        float e2v0 = 0.f, e2v1 = 0.f, e2v2 = 0.f, e2v3 = 0.f;
        #pragma unroll
        for (int kk = 0; kk < 16; kk++) {
            const int buf = kk & 1;
            const int nxt = chunk * 16 + kk + 1;
            // (1) B prefetch for next step: 4 x global dwordx4 -> regs
            if (nxt < 512) {
                const int nc = nxt >> 4, nk = nxt & 15;
                const uint4* bsrc = (const uint4*)(emb16 + ((size_t)nc << 17) + nk * 32);
                #pragma unroll
                for (int nf = 0; nf < 4; nf++) {
                    U128 u; u.u = bsrc[bgl[nf]];
                    bfp[buf ^ 1][nf] = u.b;
                }
            }
            // (2) A prefetch for next step from static zt (kk=0 pattern is
            //     chunk-invariant, so kk=15's read-ahead covers the next chunk)
            {
                const int kk1 = (kk + 1) & 15;
                const int jhi  = (kk1 * 4) & 56;
                const int jlow = ((kk1 & 1) << 2) | quad;
                #pragma unroll
                for (int mf = 0; mf < 4; mf++) {
                    U128 u; u.u = zt4[zbase[mf] + (jhi | (jlow ^ r7[mf]))];
                    afp[kk1 & 1][mf] = u.b;
                }
            }
            // e2 for this chunk's epilogue (latency hidden under MFMAs)
            if (kk == 14) {
                const int nbv = chunk * 256 + wn * 64 + col;
                e2v0 = e2[nbv];      e2v1 = e2[nbv + 16];
                e2v2 = e2[nbv + 32]; e2v3 = e2[nbv + 48];
            }
            // (3) MFMA: both operands from registers loaded last step
            __builtin_amdgcn_s_setprio(1);
            #pragma unroll
            for (int mf = 0; mf < 4; mf++)
                #pragma unroll
                for (int nf = 0; nf < 4; nf++)
                    acc[mf][nf] = __builtin_amdgcn_mfma_f32_16x16x32_bf16(
                        afp[buf][mf], bfp[buf][nf], acc[mf][nf], 0, 0, 0);
            __builtin_amdgcn_s_setprio(0);
        }
        // ---- epilogue: s = e2 - 2*dot, running argmin ----
        const int nb = chunk * 256 + wn * 64 + col;
        #pragma unroll
        for (int mf = 0; mf < 4; mf++) {
            #pragma unroll
            for (int rg = 0; rg < 4; rg++) {
                float v0 = fmaf(-2.f, acc[mf][0][rg], e2v0);
                float v1 = fmaf(-2.f, acc[mf][1][rg], e2v1);
                float v2 = fmaf(-2.f, acc[mf][2][rg], e2v2);
                float v3 = fmaf(-2.f, acc[mf][3][rg], e2v3);
                float bv = v0; int bn = 0;
                if (v1 < bv) { bv = v1; bn = 1; }
                if (v2 < bv) { bv = v2; bn = 2; }
                if (v3 < bv) { bv = v3; bn = 3; }
                if (bv < rbv[mf][rg]) { rbv[mf][rg] = bv; rbi[mf][rg] = nb + (bn << 4); }
            }
            #pragma unroll
            for (int nf = 0; nf < 4; nf++)
                acc[mf][nf] = (f32x4){0.f, 0.f, 0.f, 0.f};
        }
    }

    // ---- cross-lane argmin (over the 16 cols in each quad-group) ----
    #pragma unroll
    for (int mf = 0; mf < 4; mf++) {
        #pragma unroll
        for (int rg = 0; rg < 4; rg++) {
            float bv = rbv[mf][rg]; int bi = rbi[mf][rg];
            #pragma unroll
            for (int off = 1; off < 16; off <<= 1) {
                float ov = __shfl_xor(bv, off, 64);
                int   oi = __shfl_xor(bi, off, 64);
                if (ov < bv || (ov == bv && oi < bi)) { bv = ov; bi = oi; }
            }
            rbv[mf][rg] = bv; rbi[mf][rg] = bi;
        }
    }

    __syncthreads();   // all waves done with zt -> reuse as reduce scratch
    float* sv = (float*)zt;          // 512 floats
    int*   si = (int*)(sv + 512);    // 512 ints
    if (col == 0) {
        #pragma unroll
        for (int mf = 0; mf < 4; mf++)
            #pragma unroll
            for (int rg = 0; rg < 4; rg++) {
                int rl = wm * 64 + mf * 16 + quad * 4 + rg;
                sv[wn * 128 + rl] = rbv[mf][rg];
                si[wn * 128 + rl] = rbi[mf][rg];
            }
    }
    __syncthreads();
    float myv = 0.f;
    if (tid < 128) {
        float bv = sv[tid]; int bi = si[tid];
        #pragma unroll
        for (int wnn = 1; wnn < 4; wnn++) {
            float ov = sv[wnn * 128 + tid]; int oi = si[wnn * 128 + tid];
            if (ov < bv || (ov == bv && oi < bi)) { bv = ov; bi = oi; }
        }
        g_idx[m0 + tid] = bi;
        atomicAdd(&hist[bi], 1);
        myv = bv;
    }
    #pragma unroll
    for (int off = 32; off; off >>= 1) myv += __shfl_down(myv, off, 64);
    if (lane == 0 && w < 2) atomicAdd(&sums[1], myv);
}

// ---------------- K3: loss + perplexity ----------------
__global__ void k_final(const int* __restrict__ hist,
                        const float* __restrict__ sums,
                        float* __restrict__ out_scalars) {
    __shared__ float red[4];
    const int tid = threadIdx.x;  // 256
    float s = 0.f;
    for (int i = tid; i < NE; i += 256) {
        float e = (float)hist[i] * (1.0f / 65536.0f);
        s += e * logf(e + 1e-10f);
    }
    #pragma unroll
    for (int off = 32; off; off >>= 1) s += __shfl_down(s, off, 64);
    if ((tid & 63) == 0) red[tid >> 6] = s;
    __syncthreads();
    if (tid == 0) {
        float total = red[0] + red[1] + red[2] + red[3];
        float perp = expf(-total);
        float loss = 1.25f * (sums[0] + sums[1]) / (65536.0f * 512.0f);
        out_scalars[0] = loss;
        out_scalars[1] = perp;
    }
}

// ---------------- K4: gather z_q[n][c][t] = emb[idx[m]][c] ----------------
__global__ void k_gather(const float* __restrict__ emb,
                         const int* __restrict__ idx,
                         float* __restrict__ out) {
    // grid: (8 t-chunks of 256, 32 n); 256 threads
    __shared__ int ids[256];
    const int n  = blockIdx.y;
    const int t0 = blockIdx.x * 256;
    const int tid = threadIdx.x;
    ids[tid] = idx[n * 2048 + t0 + tid];
    __syncthreads();
    const int tq = tid & 63;   // t group of 4
    const int cg = tid >> 6;   // 0..3
    const float* e0 = emb + (size_t)ids[tq * 4 + 0] * KD;
    const float* e1 = emb + (size_t)ids[tq * 4 + 1] * KD;
    const float* e2p = emb + (size_t)ids[tq * 4 + 2] * KD;
    const float* e3 = emb + (size_t)ids[tq * 4 + 3] * KD;
    for (int cb = cg * 4; cb < KD; cb += 16) {
        float4 a = *(const float4*)(e0 + cb);
        float4 b = *(const float4*)(e1 + cb);
        float4 c = *(const float4*)(e2p + cb);
        float4 d = *(const float4*)(e3 + cb);
        float* op = out + ((size_t)(n * KD + cb)) * 2048 + t0 + tq * 4;
        float4 o0 = {a.x, b.x, c.x, d.x};
        float4 o1 = {a.y, b.y, c.y, d.y};
        float4 o2 = {a.z, b.z, c.z, d.z};
        float4 o3 = {a.w, b.w, c.w, d.w};
        *(float4*)(op)        = o0;
        *(float4*)(op + 2048) = o1;
        *(float4*)(op + 4096) = o2;
        *(float4*)(op + 6144) = o3;
    }
}

extern "C" void kernel_launch(void* const* d_in, const int* in_sizes, int n_in,
                              void* d_out, int out_size, void* d_ws, size_t ws_size,
                              hipStream_t stream) {
    (void)in_sizes; (void)n_in; (void)out_size; (void)ws_size;
    const float* z   = (const float*)d_in[0];   // 32*512*2048
    const float* emb = (const float*)d_in[1];   // 8192*512
    float* out = (float*)d_out;                 // 33554432 + 2
    char* ws = (char*)d_ws;

    float*          sums  = (float*)(ws + WS_SUMZ2);  // [0]=sumz2, [1]=sumsmin
    int*            hist  = (int*)(ws + WS_HIST);
    float*          e2    = (float*)(ws + WS_E2);
    int*            g_idx = (int*)(ws + WS_IDX);
    unsigned short* emb16 = (unsigned short*)(ws + WS_EMB16);
    unsigned short* z16   = (unsigned short*)(ws + WS_Z16);

    hipMemsetAsync(ws, 0, WS_ZEROSZ, stream);

    k_embprep<<<NE, 64, 0, stream>>>(emb, emb16, e2);
    k_zprep<<<dim3(32, 8, 32), 256, 0, stream>>>(z, z16, sums);
    k_main<<<512, 512, 0, stream>>>(z16, emb16, e2, g_idx, hist, sums);
    k_final<<<1, 256, 0, stream>>>(hist, sums, out + 33554432);
    k_gather<<<dim3(8, 32), 256, 0, stream>>>(emb, g_idx, out);
}

// Round 5
// 1327.167 us; speedup vs baseline: 1.4968x; 1.4968x over previous
//
#include <hip/hip_runtime.h>
#include <stdint.h>

#define NE 8192
#define KD 512
#define MT 65536

typedef __attribute__((ext_vector_type(8))) short bf16x8;
typedef __attribute__((ext_vector_type(4))) float f32x4;

union U128 { uint4 u; bf16x8 b; };

// ---- workspace layout (bytes) ----
#define WS_SUMZ2   0                  // float
#define WS_SUMSMIN 4                  // float
#define WS_HIST    8                  // 8192 * int
#define WS_ZEROSZ  40960              // memset region covers the above
#define WS_E2      40960              // 8192 floats
#define WS_IDX     73728              // 65536 ints
#define WS_EMB16   335872             // 8192*512 bf16 (ushort)
#define WS_Z16     8724480            // 65536*512 bf16 (ushort)
// total ws needed: 75,833,344 bytes

__device__ __forceinline__ unsigned int f2bf(float f) {
    union { float f; unsigned int u; } c; c.f = f;
    return (c.u + 0x7FFFu + ((c.u >> 16) & 1u)) >> 16;
}

// ---------------- K0: emb -> bf16, e2 = ||e||^2 ----------------
__global__ void k_embprep(const float* __restrict__ emb,
                          unsigned short* __restrict__ emb16,
                          float* __restrict__ e2) {
    const int code = blockIdx.x;
    const int lane = threadIdx.x;  // 64
    const float4* row = (const float4*)(emb + (size_t)code * KD);
    float4 a = row[lane * 2];
    float4 b = row[lane * 2 + 1];
    float s = a.x*a.x + a.y*a.y + a.z*a.z + a.w*a.w
            + b.x*b.x + b.y*b.y + b.z*b.z + b.w*b.w;
    uint4 o;
    o.x = f2bf(a.x) | (f2bf(a.y) << 16);
    o.y = f2bf(a.z) | (f2bf(a.w) << 16);
    o.z = f2bf(b.x) | (f2bf(b.y) << 16);
    o.w = f2bf(b.z) | (f2bf(b.w) << 16);
    ((uint4*)(emb16 + (size_t)code * KD))[lane] = o;
    #pragma unroll
    for (int off = 32; off; off >>= 1) s += __shfl_down(s, off, 64);
    if (lane == 0) e2[code] = s;
}

// ---------------- K1: transpose z (N,C,T) -> z16[M][K] bf16, sum z^2 ----------------
__global__ void k_zprep(const float* __restrict__ z,
                        unsigned short* __restrict__ z16,
                        float* __restrict__ sumz2) {
    // grid: (32 t-tiles, 8 c-tiles, 32 n); 256 threads; tile = 64c x 64t
    __shared__ float arr[64][65];
    __shared__ float red[4];
    const int tid = threadIdx.x;
    const int n  = blockIdx.z;
    const int c0 = blockIdx.y * 64;
    const int t0 = blockIdx.x * 64;
    const int tl4 = (tid & 15) * 4;   // t offset (16B aligned)
    const int cw  = tid >> 4;         // 0..15
    const float* base = z + ((size_t)n * KD + c0) * 2048 + t0;
    float s = 0.f;
    #pragma unroll
    for (int u = 0; u < 4; u++) {
        int c = u * 16 + cw;
        float4 v = *(const float4*)(base + (size_t)c * 2048 + tl4);
        arr[c][tl4 + 0] = v.x; arr[c][tl4 + 1] = v.y;
        arr[c][tl4 + 2] = v.z; arr[c][tl4 + 3] = v.w;
        s += v.x*v.x + v.y*v.y + v.z*v.z + v.w*v.w;
    }
    #pragma unroll
    for (int off = 32; off; off >>= 1) s += __shfl_down(s, off, 64);
    if ((tid & 63) == 0) red[tid >> 6] = s;
    __syncthreads();
    if (tid == 0) atomicAdd(sumz2, red[0] + red[1] + red[2] + red[3]);
    #pragma unroll
    for (int iter = 0; iter < 2; iter++) {
        int task = iter * 256 + tid;
        int row = task >> 3;       // t index 0..63
        int ch  = task & 7;        // uint4 chunk (8 c's)
        float f0 = arr[ch*8+0][row], f1 = arr[ch*8+1][row],
              f2v = arr[ch*8+2][row], f3 = arr[ch*8+3][row],
              f4 = arr[ch*8+4][row], f5 = arr[ch*8+5][row],
              f6 = arr[ch*8+6][row], f7 = arr[ch*8+7][row];
        uint4 o;
        o.x = f2bf(f0) | (f2bf(f1) << 16);
        o.y = f2bf(f2v) | (f2bf(f3) << 16);
        o.z = f2bf(f4) | (f2bf(f5) << 16);
        o.w = f2bf(f6) | (f2bf(f7) << 16);
        *(uint4*)(z16 + ((size_t)(n * 2048 + t0 + row)) * KD + c0 + ch * 8) = o;
    }
}

// ---------------- K2: fused GEMM + argmin (global-B, drift-controlled) ----------------
// A (z-tile) in LDS (128 KB, XOR swizzle) -> 1 block/CU, 8 waves.
// B (emb16) loaded DIRECTLY global->registers (distance-1 ping-pong).
// Round 4 failed because with ZERO barriers, wave/block drift made the
// per-XCD emb16 footprint >> 4MB L2 -> LLC-feed-bound (1.8 TB/s, FETCH 2.9GB).
// Fix: one raw s_barrier per chunk (pacing only, no vmcnt drain; zt is
// read-only so no memory semantics needed). Intra-block drift <= 1 chunk;
// blocks on an XCD self-synchronize (leader pays the L2 miss, laggards
// draft on warm L2) -> concurrent footprint ~ few*256KB << 4MB.
__global__ __launch_bounds__(512, 2) void k_main(
    const unsigned short* __restrict__ z16,   // [65536][512]
    const unsigned short* __restrict__ emb16, // [8192][512]
    const float* __restrict__ e2,             // [8192]
    int* __restrict__ g_idx,                  // [65536]
    int* __restrict__ hist,                   // [8192]
    float* __restrict__ sums)                 // ws base: [0]=sumz2, [1]=sumsmin
{
    __shared__ __align__(16) unsigned short zt[128 * 512];   // 131072 B, swizzled

    const int tid  = threadIdx.x;
    const int lane = tid & 63;
    const int w    = tid >> 6;       // 0..7
    const int wm   = w & 1;
    const int wn   = w >> 1;         // 0..3
    const int quad = lane >> 4;
    const int col  = lane & 15;
    const int m0   = blockIdx.x * 128;

    // ---- stage zt: rows m0..m0+127, full K, 16B-chunk XOR swizzle ----
    {
        const int r  = tid >> 2;             // 0..127
        const int jb = (tid & 3) << 4;       // 0,16,32,48
        const uint4* gz = (const uint4*)(z16 + (size_t)(m0 + r) * KD);
        uint4* zt4w = (uint4*)zt;
        #pragma unroll
        for (int jj = 0; jj < 16; jj++) {
            int j  = jb + jj;
            int js = (j & 56) | ((j ^ r) & 7);
            zt4w[r * 64 + js] = gz[j];
        }
    }

    f32x4 acc[4][4];
    #pragma unroll
    for (int mf = 0; mf < 4; mf++)
        #pragma unroll
        for (int nf = 0; nf < 4; nf++)
            acc[mf][nf] = (f32x4){0.f, 0.f, 0.f, 0.f};

    float rbv[4][4]; int rbi[4][4];
    #pragma unroll
    for (int mf = 0; mf < 4; mf++)
        #pragma unroll
        for (int rg = 0; rg < 4; rg++) { rbv[mf][rg] = 3.0e38f; rbi[mf][rg] = 0; }

    // A-read precompute
    int zbase[4], r7[4];
    #pragma unroll
    for (int mf = 0; mf < 4; mf++) {
        int r = wm * 64 + mf * 16 + col;
        zbase[mf] = r * 64;
        r7[mf] = r & 7;
    }
    // B global-read precompute: uint4 index of (code_local, quad) from a
    // (chunk,kk) slice base. code_local = wn*64 + nf*16 + col; each row is
    // 64 uint4; quad selects the 16B sub-chunk of the 32-elem K-slice.
    int bgl[4];
    #pragma unroll
    for (int nf = 0; nf < 4; nf++)
        bgl[nf] = (wn * 64 + nf * 16 + col) * 64 + quad;

    const uint4* zt4 = (const uint4*)zt;

    __syncthreads();   // zt published; read-only until the final reduce

    // B distance-1 register ping-pong; prologue: chunk 0, kk 0
    bf16x8 bfp[2][4];
    {
        const uint4* bsrc = (const uint4*)emb16;
        #pragma unroll
        for (int nf = 0; nf < 4; nf++) {
            U128 u; u.u = bsrc[bgl[nf]];
            bfp[0][nf] = u.b;
        }
    }

    #pragma unroll 1
    for (int chunk = 0; chunk < 32; chunk++) {
        float e2v0 = 0.f, e2v1 = 0.f, e2v2 = 0.f, e2v3 = 0.f;
        #pragma unroll
        for (int kk = 0; kk < 16; kk++) {
            const int buf = kk & 1;
            const int nxt = chunk * 16 + kk + 1;
            // (1) B prefetch for next step: 4 x global dwordx4 -> regs
            if (nxt < 512) {
                const int nc = nxt >> 4, nk = nxt & 15;
                const uint4* bsrc = (const uint4*)(emb16 + ((size_t)nc << 17) + nk * 32);
                #pragma unroll
                for (int nf = 0; nf < 4; nf++) {
                    U128 u; u.u = bsrc[bgl[nf]];
                    bfp[buf ^ 1][nf] = u.b;
                }
            }
            // (2) A-frags for THIS step from static zt
            bf16x8 af[4];
            {
                const int jhi  = (kk * 4) & 56;
                const int jlow = ((kk & 1) << 2) | quad;
                #pragma unroll
                for (int mf = 0; mf < 4; mf++) {
                    U128 u; u.u = zt4[zbase[mf] + (jhi | (jlow ^ r7[mf]))];
                    af[mf] = u.b;
                }
            }
            // e2 for this chunk's epilogue (latency hidden under MFMAs)
            if (kk == 14) {
                const int nbv = chunk * 256 + wn * 64 + col;
                e2v0 = e2[nbv];      e2v1 = e2[nbv + 16];
                e2v2 = e2[nbv + 32]; e2v3 = e2[nbv + 48];
            }
            // (3) MFMA
            __builtin_amdgcn_s_setprio(1);
            #pragma unroll
            for (int mf = 0; mf < 4; mf++)
                #pragma unroll
                for (int nf = 0; nf < 4; nf++)
                    acc[mf][nf] = __builtin_amdgcn_mfma_f32_16x16x32_bf16(
                        af[mf], bfp[buf][nf], acc[mf][nf], 0, 0, 0);
            __builtin_amdgcn_s_setprio(0);
        }
        // ---- epilogue: s = e2 - 2*dot, running argmin ----
        const int nb = chunk * 256 + wn * 64 + col;
        #pragma unroll
        for (int mf = 0; mf < 4; mf++) {
            #pragma unroll
            for (int rg = 0; rg < 4; rg++) {
                float v0 = fmaf(-2.f, acc[mf][0][rg], e2v0);
                float v1 = fmaf(-2.f, acc[mf][1][rg], e2v1);
                float v2 = fmaf(-2.f, acc[mf][2][rg], e2v2);
                float v3 = fmaf(-2.f, acc[mf][3][rg], e2v3);
                float bv = v0; int bn = 0;
                if (v1 < bv) { bv = v1; bn = 1; }
                if (v2 < bv) { bv = v2; bn = 2; }
                if (v3 < bv) { bv = v3; bn = 3; }
                if (bv < rbv[mf][rg]) { rbv[mf][rg] = bv; rbi[mf][rg] = nb + (bn << 4); }
            }
            #pragma unroll
            for (int nf = 0; nf < 4; nf++)
                acc[mf][nf] = (f32x4){0.f, 0.f, 0.f, 0.f};
        }
        // pacing barrier: bounds wave drift to <= 1 chunk so the whole
        // block's B-read footprint stays L2-resident. Raw s_barrier (no
        // waitcnt drain) — it protects no memory, only phase alignment.
        __builtin_amdgcn_s_barrier();
    }

    // ---- cross-lane argmin (over the 16 cols in each quad-group) ----
    #pragma unroll
    for (int mf = 0; mf < 4; mf++) {
        #pragma unroll
        for (int rg = 0; rg < 4; rg++) {
            float bv = rbv[mf][rg]; int bi = rbi[mf][rg];
            #pragma unroll
            for (int off = 1; off < 16; off <<= 1) {
                float ov = __shfl_xor(bv, off, 64);
                int   oi = __shfl_xor(bi, off, 64);
                if (ov < bv || (ov == bv && oi < bi)) { bv = ov; bi = oi; }
            }
            rbv[mf][rg] = bv; rbi[mf][rg] = bi;
        }
    }

    __syncthreads();   // all waves done with zt -> reuse as reduce scratch
    float* sv = (float*)zt;          // 512 floats
    int*   si = (int*)(sv + 512);    // 512 ints
    if (col == 0) {
        #pragma unroll
        for (int mf = 0; mf < 4; mf++)
            #pragma unroll
            for (int rg = 0; rg < 4; rg++) {
                int rl = wm * 64 + mf * 16 + quad * 4 + rg;
                sv[wn * 128 + rl] = rbv[mf][rg];
                si[wn * 128 + rl] = rbi[mf][rg];
            }
    }
    __syncthreads();
    float myv = 0.f;
    if (tid < 128) {
        float bv = sv[tid]; int bi = si[tid];
        #pragma unroll
        for (int wnn = 1; wnn < 4; wnn++) {
            float ov = sv[wnn * 128 + tid]; int oi = si[wnn * 128 + tid];
            if (ov < bv || (ov == bv && oi < bi)) { bv = ov; bi = oi; }
        }
        g_idx[m0 + tid] = bi;
        atomicAdd(&hist[bi], 1);
        myv = bv;
    }
    #pragma unroll
    for (int off = 32; off; off >>= 1) myv += __shfl_down(myv, off, 64);
    if (lane == 0 && w < 2) atomicAdd(&sums[1], myv);
}

// ---------------- K3: loss + perplexity ----------------
__global__ void k_final(const int* __restrict__ hist,
                        const float* __restrict__ sums,
                        float* __restrict__ out_scalars) {
    __shared__ float red[4];
    const int tid = threadIdx.x;  // 256
    float s = 0.f;
    for (int i = tid; i < NE; i += 256) {
        float e = (float)hist[i] * (1.0f / 65536.0f);
        s += e * logf(e + 1e-10f);
    }
    #pragma unroll
    for (int off = 32; off; off >>= 1) s += __shfl_down(s, off, 64);
    if ((tid & 63) == 0) red[tid >> 6] = s;
    __syncthreads();
    if (tid == 0) {
        float total = red[0] + red[1] + red[2] + red[3];
        float perp = expf(-total);
        float loss = 1.25f * (sums[0] + sums[1]) / (65536.0f * 512.0f);
        out_scalars[0] = loss;
        out_scalars[1] = perp;
    }
}

// ---------------- K4: gather z_q[n][c][t] = emb[idx[m]][c] ----------------
__global__ void k_gather(const float* __restrict__ emb,
                         const int* __restrict__ idx,
                         float* __restrict__ out) {
    // grid: (8 t-chunks of 256, 32 n); 256 threads
    __shared__ int ids[256];
    const int n  = blockIdx.y;
    const int t0 = blockIdx.x * 256;
    const int tid = threadIdx.x;
    ids[tid] = idx[n * 2048 + t0 + tid];
    __syncthreads();
    const int tq = tid & 63;   // t group of 4
    const int cg = tid >> 6;   // 0..3
    const float* e0 = emb + (size_t)ids[tq * 4 + 0] * KD;
    const float* e1 = emb + (size_t)ids[tq * 4 + 1] * KD;
    const float* e2p = emb + (size_t)ids[tq * 4 + 2] * KD;
    const float* e3 = emb + (size_t)ids[tq * 4 + 3] * KD;
    for (int cb = cg * 4; cb < KD; cb += 16) {
        float4 a = *(const float4*)(e0 + cb);
        float4 b = *(const float4*)(e1 + cb);
        float4 c = *(const float4*)(e2p + cb);
        float4 d = *(const float4*)(e3 + cb);
        float* op = out + ((size_t)(n * KD + cb)) * 2048 + t0 + tq * 4;
        float4 o0 = {a.x, b.x, c.x, d.x};
        float4 o1 = {a.y, b.y, c.y, d.y};
        float4 o2 = {a.z, b.z, c.z, d.z};
        float4 o3 = {a.w, b.w, c.w, d.w};
        *(float4*)(op)        = o0;
        *(float4*)(op + 2048) = o1;
        *(float4*)(op + 4096) = o2;
        *(float4*)(op + 6144) = o3;
    }
}

extern "C" void kernel_launch(void* const* d_in, const int* in_sizes, int n_in,
                              void* d_out, int out_size, void* d_ws, size_t ws_size,
                              hipStream_t stream) {
    (void)in_sizes; (void)n_in; (void)out_size; (void)ws_size;
    const float* z   = (const float*)d_in[0];   // 32*512*2048
    const float* emb = (const float*)d_in[1];   // 8192*512
    float* out = (float*)d_out;                 // 33554432 + 2
    char* ws = (char*)d_ws;

    float*          sums  = (float*)(ws + WS_SUMZ2);  // [0]=sumz2, [1]=sumsmin
    int*            hist  = (int*)(ws + WS_HIST);
    float*          e2    = (float*)(ws + WS_E2);
    int*            g_idx = (int*)(ws + WS_IDX);
    unsigned short* emb16 = (unsigned short*)(ws + WS_EMB16);
    unsigned short* z16   = (unsigned short*)(ws + WS_Z16);

    hipMemsetAsync(ws, 0, WS_ZEROSZ, stream);

    k_embprep<<<NE, 64, 0, stream>>>(emb, emb16, e2);
    k_zprep<<<dim3(32, 8, 32), 256, 0, stream>>>(z, z16, sums);
    k_main<<<512, 512, 0, stream>>>(z16, emb16, e2, g_idx, hist, sums);
    k_final<<<1, 256, 0, stream>>>(hist, sums, out + 33554432);
    k_gather<<<dim3(8, 32), 256, 0, stream>>>(emb, g_idx, out);
}

// Round 6
// 914.507 us; speedup vs baseline: 2.1722x; 1.4512x over previous
//
#include <hip/hip_runtime.h>
#include <stdint.h>

#define NE 8192
#define KD 512
#define MT 65536

typedef __attribute__((ext_vector_type(8))) short bf16x8;
typedef __attribute__((ext_vector_type(4))) float f32x4;

union U128 { uint4 u; bf16x8 b; };

// ---- workspace layout (bytes) ----
#define WS_SUMZ2   0                  // float
#define WS_SUMSMIN 4                  // float
#define WS_HIST    8                  // 8192 * int
#define WS_ZEROSZ  40960              // memset region covers the above
#define WS_E2      40960              // 8192 floats
#define WS_IDX     73728              // 65536 ints
#define WS_EMB16   335872             // 8192*512 bf16 (ushort)
#define WS_Z16     8724480            // 65536*512 bf16 (ushort)
// total ws needed: 75,833,344 bytes

__device__ __forceinline__ unsigned int f2bf(float f) {
    union { float f; unsigned int u; } c; c.f = f;
    return (c.u + 0x7FFFu + ((c.u >> 16) & 1u)) >> 16;
}

__device__ __forceinline__ float bf2f(unsigned short h) {
    union { float f; unsigned int u; } c; c.u = ((unsigned int)h) << 16;
    return c.f;
}

__device__ __forceinline__ void load_lds16(const void* g, void* l) {
    __builtin_amdgcn_global_load_lds((const __attribute__((address_space(1))) void*)g,
                                     (__attribute__((address_space(3))) void*)l,
                                     16, 0, 0);
}

// ---------------- K0: emb -> bf16, e2 = ||e||^2 ----------------
__global__ void k_embprep(const float* __restrict__ emb,
                          unsigned short* __restrict__ emb16,
                          float* __restrict__ e2) {
    const int code = blockIdx.x;
    const int lane = threadIdx.x;  // 64
    const float4* row = (const float4*)(emb + (size_t)code * KD);
    float4 a = row[lane * 2];
    float4 b = row[lane * 2 + 1];
    float s = a.x*a.x + a.y*a.y + a.z*a.z + a.w*a.w
            + b.x*b.x + b.y*b.y + b.z*b.z + b.w*b.w;
    uint4 o;
    o.x = f2bf(a.x) | (f2bf(a.y) << 16);
    o.y = f2bf(a.z) | (f2bf(a.w) << 16);
    o.z = f2bf(b.x) | (f2bf(b.y) << 16);
    o.w = f2bf(b.z) | (f2bf(b.w) << 16);
    ((uint4*)(emb16 + (size_t)code * KD))[lane] = o;
    #pragma unroll
    for (int off = 32; off; off >>= 1) s += __shfl_down(s, off, 64);
    if (lane == 0) e2[code] = s;
}

// ---------------- K1: transpose z (N,C,T) -> z16[M][K] bf16, sum z^2 ----------------
__global__ void k_zprep(const float* __restrict__ z,
                        unsigned short* __restrict__ z16,
                        float* __restrict__ sumz2) {
    // grid: (32 t-tiles, 8 c-tiles, 32 n); 256 threads; tile = 64c x 64t
    __shared__ float arr[64][65];
    __shared__ float red[4];
    const int tid = threadIdx.x;
    const int n  = blockIdx.z;
    const int c0 = blockIdx.y * 64;
    const int t0 = blockIdx.x * 64;
    const int tl4 = (tid & 15) * 4;   // t offset (16B aligned)
    const int cw  = tid >> 4;         // 0..15
    const float* base = z + ((size_t)n * KD + c0) * 2048 + t0;
    float s = 0.f;
    #pragma unroll
    for (int u = 0; u < 4; u++) {
        int c = u * 16 + cw;
        float4 v = *(const float4*)(base + (size_t)c * 2048 + tl4);
        arr[c][tl4 + 0] = v.x; arr[c][tl4 + 1] = v.y;
        arr[c][tl4 + 2] = v.z; arr[c][tl4 + 3] = v.w;
        s += v.x*v.x + v.y*v.y + v.z*v.z + v.w*v.w;
    }
    #pragma unroll
    for (int off = 32; off; off >>= 1) s += __shfl_down(s, off, 64);
    if ((tid & 63) == 0) red[tid >> 6] = s;
    __syncthreads();
    if (tid == 0) atomicAdd(sumz2, red[0] + red[1] + red[2] + red[3]);
    #pragma unroll
    for (int iter = 0; iter < 2; iter++) {
        int task = iter * 256 + tid;
        int row = task >> 3;       // t index 0..63
        int ch  = task & 7;        // uint4 chunk (8 c's)
        float f0 = arr[ch*8+0][row], f1 = arr[ch*8+1][row],
              f2v = arr[ch*8+2][row], f3 = arr[ch*8+3][row],
              f4 = arr[ch*8+4][row], f5 = arr[ch*8+5][row],
              f6 = arr[ch*8+6][row], f7 = arr[ch*8+7][row];
        uint4 o;
        o.x = f2bf(f0) | (f2bf(f1) << 16);
        o.y = f2bf(f2v) | (f2bf(f3) << 16);
        o.z = f2bf(f4) | (f2bf(f5) << 16);
        o.w = f2bf(f6) | (f2bf(f7) << 16);
        *(uint4*)(z16 + ((size_t)(n * 2048 + t0 + row)) * KD + c0 + ch * 8) = o;
    }
}

// ---------------- K2: fused GEMM + argmin (ring-4 et, counted vmcnt) ----------------
// A K-slices kk=0..3 (K 0..127) live in REGISTERS (areg, loaded once from z16);
// zt holds only K 128..511 (96 KB) -> et gets a 4-buffer ring (64 KB, total
// exactly 160 KB). Staging distance-2 with raw s_barrier + counted vmcnt:
// one staging pair is ALWAYS in flight across the barrier (T4), ~2 steps of
// latency slack. buf = kk&3 is compile-time (chunk*16 % 4 == 0).
// Hazards: writes at step s target buf[(s+2)&3], last read at s-2, separated
// by 2 barriers; reads of buf[s&3] gated by each wave's vmcnt wait + barrier.
__global__ __launch_bounds__(512, 2) void k_main(
    const unsigned short* __restrict__ z16,   // [65536][512]
    const unsigned short* __restrict__ emb16, // [8192][512]
    const float* __restrict__ e2,             // [8192]
    int* __restrict__ g_idx,                  // [65536]
    int* __restrict__ hist,                   // [8192]
    float* __restrict__ sums)                 // ws base: [0]=sumz2, [1]=sumsmin
{
    __shared__ __align__(16) unsigned short zt[128 * 384];   // 98304 B: K 128..511, swizzled
    __shared__ __align__(16) unsigned short et[4][256 * 32]; // 65536 B, rot-swizzled ring

    const int tid  = threadIdx.x;
    const int lane = tid & 63;
    const int w    = tid >> 6;       // 0..7
    const int wm   = w & 1;
    const int wn   = w >> 1;         // 0..3
    const int quad = lane >> 4;
    const int col  = lane & 15;
    const int m0   = blockIdx.x * 128;

    // ---- stage zt: rows m0..m0+127, K 128..511 (48 uint4/row), XOR swizzle ----
    {
        const int r  = tid >> 2;             // 0..127
        const int jb = (tid & 3) * 12;       // 0,12,24,36
        const uint4* gz = (const uint4*)(z16 + (size_t)(m0 + r) * KD);
        uint4* zt4w = (uint4*)zt;
        #pragma unroll
        for (int jj = 0; jj < 12; jj++) {
            int j  = jb + jj;                          // 0..47
            int js = (j & 56) | ((j ^ r) & 7);         // bijective per 8-block (48 = 6*8)
            zt4w[r * 48 + js] = gz[16 + j];            // source K-offset 128 elems
        }
    }

    // ---- A register cache: kk 0..3 (K 0..127), fragment layout, direct from z16 ----
    bf16x8 areg[4][4];
    {
        const uint4* gz4 = (const uint4*)z16;
        #pragma unroll
        for (int kk = 0; kk < 4; kk++)
            #pragma unroll
            for (int mf = 0; mf < 4; mf++) {
                int row = m0 + wm * 64 + mf * 16 + col;
                U128 u; u.u = gz4[((size_t)row << 6) + kk * 4 + quad];
                areg[kk][mf] = u.b;
            }
    }

    // ---- et staging address precompute (champion mapping, ring dest) ----
    const int st_nl0 = w * 16 + (lane >> 2);                 // row within 128-half
    const int st_q8  = ((((lane & 3) - ((st_nl0 >> 1) & 3)) & 3)) * 8;
    unsigned short* const st_base = &et[0][0] + w * 512 + lane * 8;

    f32x4 acc[4][4];
    #pragma unroll
    for (int mf = 0; mf < 4; mf++)
        #pragma unroll
        for (int nf = 0; nf < 4; nf++)
            acc[mf][nf] = (f32x4){0.f, 0.f, 0.f, 0.f};

    float rbv[4][4]; int rbi[4][4];
    #pragma unroll
    for (int mf = 0; mf < 4; mf++)
        #pragma unroll
        for (int rg = 0; rg < 4; rg++) { rbv[mf][rg] = 3.0e38f; rbi[mf][rg] = 0; }

    // A-read precompute (zt rows of 48 uint4)
    int zbase[4], r7[4];
    #pragma unroll
    for (int mf = 0; mf < 4; mf++) {
        int r = wm * 64 + mf * 16 + col;
        zbase[mf] = r * 48;
        r7[mf] = r & 7;
    }
    // B-read precompute (rotation swizzle)
    int bidx[4];
    #pragma unroll
    for (int nf = 0; nf < 4; nf++) {
        int nn = wn * 64 + nf * 16 + col;
        bidx[nf] = nn * 4 + ((quad + (nn >> 1)) & 3);
    }

    const uint4* zt4 = (const uint4*)zt;

    // ---- prologue: stage steps 0 and 1 into buf0, buf1; full drain ----
    #pragma unroll
    for (int s = 0; s < 2; s++) {
        const size_t koff = (size_t)(s & 15) * 32 + st_q8;
        const unsigned short* g0 = emb16 + (((size_t)(st_nl0)) << 9) + koff;
        const unsigned short* g1 = emb16 + (((size_t)(128 + st_nl0)) << 9) + koff;
        load_lds16(g0, st_base + s * 8192);
        load_lds16(g1, st_base + s * 8192 + 4096);
    }
    __syncthreads();   // zt + areg deps handled; buf0/buf1 staged & drained

    #pragma unroll 1
    for (int chunk = 0; chunk < 32; chunk++) {
        float e2v0 = 0.f, e2v1 = 0.f, e2v2 = 0.f, e2v3 = 0.f;
        #pragma unroll
        for (int kk = 0; kk < 16; kk++) {
            // (1) counted wait + barrier: my pair for THIS step has landed
            //     (in-order vmcnt retirement); pair for step+1 stays in flight.
            //     kk==15: the 4 e2 loads (issued at kk14, after pair) are newer.
            if (kk == 15) {
                asm volatile("s_waitcnt vmcnt(6)\n\ts_barrier" ::: "memory");
            } else {
                asm volatile("s_waitcnt vmcnt(2)\n\ts_barrier" ::: "memory");
            }
            // (2) issue staging for step s+2 into buf (kk+2)&3 (wrapped dummy
            //     at the tail keeps vmcnt counting uniform; lands before the
            //     post-loop __syncthreads drains, so no reduce-scratch hazard)
            {
                const int nxt = (chunk * 16 + kk + 2) & 511;
                const int nc = nxt >> 4, nk = nxt & 15;
                const size_t koff = (size_t)nk * 32 + st_q8;
                const unsigned short* g0 = emb16 + (((size_t)(nc * 256 + st_nl0)) << 9) + koff;
                const unsigned short* g1 = emb16 + (((size_t)(nc * 256 + 128 + st_nl0)) << 9) + koff;
                unsigned short* d = st_base + ((kk + 2) & 3) * 8192;
                load_lds16(g0, d);
                load_lds16(g1, d + 4096);
            }
            // e2 for this chunk's epilogue — issued AFTER the staging pair
            if (kk == 14) {
                const int nbv = chunk * 256 + wn * 64 + col;
                e2v0 = e2[nbv];      e2v1 = e2[nbv + 16];
                e2v2 = e2[nbv + 32]; e2v3 = e2[nbv + 48];
            }
            // (3) B-frag reads for THIS step from buf kk&3
            bf16x8 bfv[4];
            {
                const uint4* ebuf = (const uint4*)(&et[0][0] + (kk & 3) * 8192);
                #pragma unroll
                for (int nf = 0; nf < 4; nf++) {
                    U128 u; u.u = ebuf[bidx[nf]];
                    bfv[nf] = u.b;
                }
            }
            // (4) A-frags: registers for kk<4, zt for kk>=4
            bf16x8 af[4];
            if (kk < 4) {
                #pragma unroll
                for (int mf = 0; mf < 4; mf++) af[mf] = areg[kk][mf];
            } else {
                const int zkk  = kk - 4;
                const int jhi  = (zkk * 4) & 56;
                const int jlow = ((kk & 1) << 2) | quad;
                #pragma unroll
                for (int mf = 0; mf < 4; mf++) {
                    U128 u; u.u = zt4[zbase[mf] + (jhi | (jlow ^ r7[mf]))];
                    af[mf] = u.b;
                }
            }
            // (5) MFMA
            __builtin_amdgcn_s_setprio(1);
            #pragma unroll
            for (int mf = 0; mf < 4; mf++)
                #pragma unroll
                for (int nf = 0; nf < 4; nf++)
                    acc[mf][nf] = __builtin_amdgcn_mfma_f32_16x16x32_bf16(
                        af[mf], bfv[nf], acc[mf][nf], 0, 0, 0);
            __builtin_amdgcn_s_setprio(0);
        }
        // ---- epilogue: s = e2 - 2*dot, running argmin ----
        const int nb = chunk * 256 + wn * 64 + col;
        #pragma unroll
        for (int mf = 0; mf < 4; mf++) {
            #pragma unroll
            for (int rg = 0; rg < 4; rg++) {
                float v0 = fmaf(-2.f, acc[mf][0][rg], e2v0);
                float v1 = fmaf(-2.f, acc[mf][1][rg], e2v1);
                float v2 = fmaf(-2.f, acc[mf][2][rg], e2v2);
                float v3 = fmaf(-2.f, acc[mf][3][rg], e2v3);
                float bv = v0; int bn = 0;
                if (v1 < bv) { bv = v1; bn = 1; }
                if (v2 < bv) { bv = v2; bn = 2; }
                if (v3 < bv) { bv = v3; bn = 3; }
                if (bv < rbv[mf][rg]) { rbv[mf][rg] = bv; rbi[mf][rg] = nb + (bn << 4); }
            }
            #pragma unroll
            for (int nf = 0; nf < 4; nf++)
                acc[mf][nf] = (f32x4){0.f, 0.f, 0.f, 0.f};
        }
    }

    // ---- cross-lane argmin (over the 16 cols in each quad-group) ----
    #pragma unroll
    for (int mf = 0; mf < 4; mf++) {
        #pragma unroll
        for (int rg = 0; rg < 4; rg++) {
            float bv = rbv[mf][rg]; int bi = rbi[mf][rg];
            #pragma unroll
            for (int off = 1; off < 16; off <<= 1) {
                float ov = __shfl_xor(bv, off, 64);
                int   oi = __shfl_xor(bi, off, 64);
                if (ov < bv || (ov == bv && oi < bi)) { bv = ov; bi = oi; }
            }
            rbv[mf][rg] = bv; rbi[mf][rg] = bi;
        }
    }

    __syncthreads();   // FULL drain: tail dummy stages landed, all reads done
    float* sv = (float*)&et[0][0];   // 512 floats (et reused as scratch)
    int*   si = (int*)(sv + 512);    // 512 ints
    if (col == 0) {
        #pragma unroll
        for (int mf = 0; mf < 4; mf++)
            #pragma unroll
            for (int rg = 0; rg < 4; rg++) {
                int rl = wm * 64 + mf * 16 + quad * 4 + rg;
                sv[wn * 128 + rl] = rbv[mf][rg];
                si[wn * 128 + rl] = rbi[mf][rg];
            }
    }
    __syncthreads();
    float myv = 0.f;
    if (tid < 128) {
        float bv = sv[tid]; int bi = si[tid];
        #pragma unroll
        for (int wnn = 1; wnn < 4; wnn++) {
            float ov = sv[wnn * 128 + tid]; int oi = si[wnn * 128 + tid];
            if (ov < bv || (ov == bv && oi < bi)) { bv = ov; bi = oi; }
        }
        g_idx[m0 + tid] = bi;
        atomicAdd(&hist[bi], 1);
        myv = bv;
    }
    #pragma unroll
    for (int off = 32; off; off >>= 1) myv += __shfl_down(myv, off, 64);
    if (lane == 0 && w < 2) atomicAdd(&sums[1], myv);
}

// ---------------- K3: loss + perplexity ----------------
__global__ void k_final(const int* __restrict__ hist,
                        const float* __restrict__ sums,
                        float* __restrict__ out_scalars) {
    __shared__ float red[4];
    const int tid = threadIdx.x;  // 256
    float s = 0.f;
    for (int i = tid; i < NE; i += 256) {
        float e = (float)hist[i] * (1.0f / 65536.0f);
        s += e * logf(e + 1e-10f);
    }
    #pragma unroll
    for (int off = 32; off; off >>= 1) s += __shfl_down(s, off, 64);
    if ((tid & 63) == 0) red[tid >> 6] = s;
    __syncthreads();
    if (tid == 0) {
        float total = red[0] + red[1] + red[2] + red[3];
        float perp = expf(-total);
        float loss = 1.25f * (sums[0] + sums[1]) / (65536.0f * 512.0f);
        out_scalars[0] = loss;
        out_scalars[1] = perp;
    }
}

// ---------------- K4: gather z_q[n][c][t] = bf2f(emb16[idx[m]][c]) ----------------
// Reads the bf16 codebook (half the gather traffic of f32 emb); error per
// element <= 2^-9 * 1.2e-4 ~ 2.4e-7, negligible vs tolerance.
__global__ void k_gather(const unsigned short* __restrict__ emb16,
                         const int* __restrict__ idx,
                         float* __restrict__ out) {
    // grid: (8 t-chunks of 256, 32 n); 256 threads
    __shared__ int ids[256];
    const int n  = blockIdx.y;
    const int t0 = blockIdx.x * 256;
    const int tid = threadIdx.x;
    ids[tid] = idx[n * 2048 + t0 + tid];
    __syncthreads();
    const int tq = tid & 63;   // t group of 4
    const int cg = tid >> 6;   // 0..3
    const unsigned short* e0 = emb16 + (size_t)ids[tq * 4 + 0] * KD;
    const unsigned short* e1 = emb16 + (size_t)ids[tq * 4 + 1] * KD;
    const unsigned short* e2p = emb16 + (size_t)ids[tq * 4 + 2] * KD;
    const unsigned short* e3 = emb16 + (size_t)ids[tq * 4 + 3] * KD;
    for (int cb = cg * 8; cb < KD; cb += 32) {
        uint4 a = *(const uint4*)(e0 + cb);
        uint4 b = *(const uint4*)(e1 + cb);
        uint4 c = *(const uint4*)(e2p + cb);
        uint4 d = *(const uint4*)(e3 + cb);
        const unsigned short* pa = (const unsigned short*)&a;
        const unsigned short* pb = (const unsigned short*)&b;
        const unsigned short* pc = (const unsigned short*)&c;
        const unsigned short* pd = (const unsigned short*)&d;
        float* op = out + ((size_t)(n * KD + cb)) * 2048 + t0 + tq * 4;
        #pragma unroll
        for (int j = 0; j < 8; j++) {
            float4 o = { bf2f(pa[j]), bf2f(pb[j]), bf2f(pc[j]), bf2f(pd[j]) };
            *(float4*)(op + (size_t)j * 2048) = o;
        }
    }
}

extern "C" void kernel_launch(void* const* d_in, const int* in_sizes, int n_in,
                              void* d_out, int out_size, void* d_ws, size_t ws_size,
                              hipStream_t stream) {
    (void)in_sizes; (void)n_in; (void)out_size; (void)ws_size;
    const float* z   = (const float*)d_in[0];   // 32*512*2048
    const float* emb = (const float*)d_in[1];   // 8192*512
    float* out = (float*)d_out;                 // 33554432 + 2
    char* ws = (char*)d_ws;

    float*          sums  = (float*)(ws + WS_SUMZ2);  // [0]=sumz2, [1]=sumsmin
    int*            hist  = (int*)(ws + WS_HIST);
    float*          e2    = (float*)(ws + WS_E2);
    int*            g_idx = (int*)(ws + WS_IDX);
    unsigned short* emb16 = (unsigned short*)(ws + WS_EMB16);
    unsigned short* z16   = (unsigned short*)(ws + WS_Z16);

    hipMemsetAsync(ws, 0, WS_ZEROSZ, stream);

    k_embprep<<<NE, 64, 0, stream>>>(emb, emb16, e2);
    k_zprep<<<dim3(32, 8, 32), 256, 0, stream>>>(z, z16, sums);
    k_main<<<512, 512, 0, stream>>>(z16, emb16, e2, g_idx, hist, sums);
    k_final<<<1, 256, 0, stream>>>(hist, sums, out + 33554432);
    k_gather<<<dim3(8, 32), 256, 0, stream>>>(emb16, g_idx, out);
}